// Round 3
// baseline (3148.593 us; speedup 1.0000x reference)
//
#include <hip/hip_runtime.h>
#include <hip/hip_bf16.h>

#define HID 64
#define IN_EMB 128
#define IN_DIM 130
#define ROWS_PER_BKT 128
#define LOG_RPB 7
#define MAX_BKT 1024          // 100000/128 = 782 buckets actually used
#define PART_CHUNK 16384      // edges per partition block

typedef __hip_bfloat16 bf16;

// ---------------- coarse histogram over row-buckets ----------------
__global__ __launch_bounds__(256) void bhist_kernel(const int* __restrict__ row,
                                                    int* __restrict__ bcnt,
                                                    int nE, int nbkt) {
  __shared__ int h[MAX_BKT];
  for (int i = threadIdx.x; i < nbkt; i += 256) h[i] = 0;
  __syncthreads();
  const int stride = gridDim.x * 256;
  for (int e = blockIdx.x * 256 + threadIdx.x; e < nE; e += stride)
    atomicAdd(&h[row[e] >> LOG_RPB], 1);
  __syncthreads();
  for (int i = threadIdx.x; i < nbkt; i += 256)
    if (h[i]) atomicAdd(&bcnt[i], h[i]);
}

// ---------------- exclusive scan of 782 bucket counts (1 block) --------------
__global__ __launch_bounds__(1024) void bscan_kernel(const int* __restrict__ bcnt,
                                                     int* __restrict__ bstart,
                                                     int* __restrict__ bcur, int nbkt) {
  __shared__ int s[1024];
  const int t = threadIdx.x;
  const int v = (t < nbkt) ? bcnt[t] : 0;
  s[t] = v;
  __syncthreads();
  for (int off = 1; off < 1024; off <<= 1) {
    int u = (t >= off) ? s[t - off] : 0;
    __syncthreads();
    s[t] += u;
    __syncthreads();
  }
  if (t < nbkt) { int ex = s[t] - v; bstart[t] = ex; bcur[t] = ex; }
  if (t == 0) bstart[nbkt] = s[1023];   // == nE
}

// ---------------- partition edges into row-buckets (coalesced runs) ----------
// packed edge: .x = col | (local_row << 20), .y = bits(val)
__global__ __launch_bounds__(256) void partition_kernel(
    const int* __restrict__ row, const int* __restrict__ col,
    const float* __restrict__ vals, int* __restrict__ bcur,
    int2* __restrict__ tmp, int nE) {
  __shared__ int h[MAX_BKT];
  __shared__ int cur[MAX_BKT];
  const int t = threadIdx.x;
  const int base = blockIdx.x * PART_CHUNK;
  for (int i = t; i < MAX_BKT; i += 256) h[i] = 0;
  __syncthreads();
  // phase A: local bucket histogram
  for (int k = 0; k < PART_CHUNK / 256; ++k) {
    int e = base + k * 256 + t;
    if (e < nE) atomicAdd(&h[row[e] >> LOG_RPB], 1);
  }
  __syncthreads();
  // phase B: reserve one contiguous run per non-empty bucket
  for (int b = t; b < MAX_BKT; b += 256)
    if (h[b] > 0) cur[b] = atomicAdd(&bcur[b], h[b]);
  __syncthreads();
  // phase C: re-read edges, write grouped (runs are contiguous ~170B chunks)
  for (int k = 0; k < PART_CHUNK / 256; ++k) {
    int e = base + k * 256 + t;
    if (e < nE) {
      int r = row[e];
      int b = r >> LOG_RPB;
      int p = atomicAdd(&cur[b], 1);
      tmp[p] = make_int2(col[e] | ((r & (ROWS_PER_BKT - 1)) << 20),
                         __float_as_int(vals[e]));
    }
  }
}

// ---------------- Linear1: bf16 activations out ------------------------------
__global__ __launch_bounds__(256) void lin1_kernel(
    const float* __restrict__ emb, const float* __restrict__ deg,
    const float* __restrict__ seed, const float* __restrict__ W1,
    const float* __restrict__ b1, bf16* __restrict__ out, int n) {
  __shared__ float sW[IN_DIM * HID];
  for (int i = threadIdx.x; i < IN_DIM * HID; i += 256) sW[i] = W1[i];
  __syncthreads();
  const int lane = threadIdx.x & 63;
  const int g    = threadIdx.x >> 6;
  const int base = blockIdx.x * 32;
  for (int nn = g; nn < 32; nn += 4) {
    const int node = base + nn;
    if (node >= n) continue;
    float acc = b1[lane];
    const float* e = emb + (size_t)node * IN_EMB;
#pragma unroll 8
    for (int k = 0; k < IN_EMB; ++k) acc += e[k] * sW[k * HID + lane];
    acc += deg[node]  * sW[IN_EMB * HID + lane];
    acc += seed[node] * sW[(IN_EMB + 1) * HID + lane];
    out[(size_t)node * HID + lane] = __float2bfloat16(acc);
  }
}

// ---------------- SpMM1 (bucketed, LDS tile) + fused ReLU + Linear2 ----------
__global__ __launch_bounds__(256) void spmm1_kernel(
    const int* __restrict__ bstart, const int2* __restrict__ tmp,
    const bf16* __restrict__ x, const float* __restrict__ W2,
    const float* __restrict__ b2, bf16* __restrict__ xout, int n) {
  __shared__ float yt[ROWS_PER_BKT * HID];   // 32 KB output tile
  __shared__ float sW[HID * HID];            // 16 KB W2
  const int t = threadIdx.x;
  const int lane = t & 63;
  const int g = t >> 6;
  for (int i = t; i < HID * HID; i += 256) sW[i] = W2[i];
  for (int i = t; i < ROWS_PER_BKT * HID; i += 256) yt[i] = 0.f;
  __syncthreads();

  const int b = blockIdx.x;
  const int start = bstart[b];
  const int end   = bstart[b + 1];
  for (int i = start + g * 8; i < end; i += 32) {
    if (i + 8 <= end) {
      int2 e0 = tmp[i],   e1 = tmp[i+1], e2 = tmp[i+2], e3 = tmp[i+3];
      int2 e4 = tmp[i+4], e5 = tmp[i+5], e6 = tmp[i+6], e7 = tmp[i+7];
      float g0 = __bfloat162float(x[(size_t)(e0.x & 0xFFFFF) * HID + lane]);
      float g1 = __bfloat162float(x[(size_t)(e1.x & 0xFFFFF) * HID + lane]);
      float g2 = __bfloat162float(x[(size_t)(e2.x & 0xFFFFF) * HID + lane]);
      float g3 = __bfloat162float(x[(size_t)(e3.x & 0xFFFFF) * HID + lane]);
      float g4 = __bfloat162float(x[(size_t)(e4.x & 0xFFFFF) * HID + lane]);
      float g5 = __bfloat162float(x[(size_t)(e5.x & 0xFFFFF) * HID + lane]);
      float g6 = __bfloat162float(x[(size_t)(e6.x & 0xFFFFF) * HID + lane]);
      float g7 = __bfloat162float(x[(size_t)(e7.x & 0xFFFFF) * HID + lane]);
      atomicAdd(&yt[((e0.x >> 20) << 6) + lane], __int_as_float(e0.y) * g0);
      atomicAdd(&yt[((e1.x >> 20) << 6) + lane], __int_as_float(e1.y) * g1);
      atomicAdd(&yt[((e2.x >> 20) << 6) + lane], __int_as_float(e2.y) * g2);
      atomicAdd(&yt[((e3.x >> 20) << 6) + lane], __int_as_float(e3.y) * g3);
      atomicAdd(&yt[((e4.x >> 20) << 6) + lane], __int_as_float(e4.y) * g4);
      atomicAdd(&yt[((e5.x >> 20) << 6) + lane], __int_as_float(e5.y) * g5);
      atomicAdd(&yt[((e6.x >> 20) << 6) + lane], __int_as_float(e6.y) * g6);
      atomicAdd(&yt[((e7.x >> 20) << 6) + lane], __int_as_float(e7.y) * g7);
    } else {
      for (int j = 0; j < end - i; ++j) {
        int2 e0 = tmp[i + j];
        float g0 = __bfloat162float(x[(size_t)(e0.x & 0xFFFFF) * HID + lane]);
        atomicAdd(&yt[((e0.x >> 20) << 6) + lane], __int_as_float(e0.y) * g0);
      }
    }
  }
  __syncthreads();

  // epilogue: x2[node] = relu(y1[node]) @ W2 + b2, stored bf16
  const int node0 = b * ROWS_PER_BKT;
  const float bias = b2[lane];
  for (int nn = g; nn < ROWS_PER_BKT; nn += 4) {
    const int node = node0 + nn;
    if (node >= n) break;
    float acc = bias;
    const float* yr = &yt[nn * HID];
#pragma unroll 8
    for (int k = 0; k < HID; ++k)
      acc += fmaxf(yr[k], 0.f) * sW[k * HID + lane];
    xout[(size_t)node * HID + lane] = __float2bfloat16(acc);
  }
}

// ---------------- SpMM2 (bucketed) + fused ReLU + global reduce --------------
__global__ __launch_bounds__(256) void spmm2_kernel(
    const int* __restrict__ bstart, const int2* __restrict__ tmp,
    const bf16* __restrict__ x, const float* __restrict__ Wout,
    const float* __restrict__ bout, float* __restrict__ out, int n) {
  __shared__ float yt[ROWS_PER_BKT * HID];
  const int t = threadIdx.x;
  const int lane = t & 63;
  const int g = t >> 6;
  for (int i = t; i < ROWS_PER_BKT * HID; i += 256) yt[i] = 0.f;
  __syncthreads();

  const int b = blockIdx.x;
  const int start = bstart[b];
  const int end   = bstart[b + 1];
  for (int i = start + g * 8; i < end; i += 32) {
    if (i + 8 <= end) {
      int2 e0 = tmp[i],   e1 = tmp[i+1], e2 = tmp[i+2], e3 = tmp[i+3];
      int2 e4 = tmp[i+4], e5 = tmp[i+5], e6 = tmp[i+6], e7 = tmp[i+7];
      float g0 = __bfloat162float(x[(size_t)(e0.x & 0xFFFFF) * HID + lane]);
      float g1 = __bfloat162float(x[(size_t)(e1.x & 0xFFFFF) * HID + lane]);
      float g2 = __bfloat162float(x[(size_t)(e2.x & 0xFFFFF) * HID + lane]);
      float g3 = __bfloat162float(x[(size_t)(e3.x & 0xFFFFF) * HID + lane]);
      float g4 = __bfloat162float(x[(size_t)(e4.x & 0xFFFFF) * HID + lane]);
      float g5 = __bfloat162float(x[(size_t)(e5.x & 0xFFFFF) * HID + lane]);
      float g6 = __bfloat162float(x[(size_t)(e6.x & 0xFFFFF) * HID + lane]);
      float g7 = __bfloat162float(x[(size_t)(e7.x & 0xFFFFF) * HID + lane]);
      atomicAdd(&yt[((e0.x >> 20) << 6) + lane], __int_as_float(e0.y) * g0);
      atomicAdd(&yt[((e1.x >> 20) << 6) + lane], __int_as_float(e1.y) * g1);
      atomicAdd(&yt[((e2.x >> 20) << 6) + lane], __int_as_float(e2.y) * g2);
      atomicAdd(&yt[((e3.x >> 20) << 6) + lane], __int_as_float(e3.y) * g3);
      atomicAdd(&yt[((e4.x >> 20) << 6) + lane], __int_as_float(e4.y) * g4);
      atomicAdd(&yt[((e5.x >> 20) << 6) + lane], __int_as_float(e5.y) * g5);
      atomicAdd(&yt[((e6.x >> 20) << 6) + lane], __int_as_float(e6.y) * g6);
      atomicAdd(&yt[((e7.x >> 20) << 6) + lane], __int_as_float(e7.y) * g7);
    } else {
      for (int j = 0; j < end - i; ++j) {
        int2 e0 = tmp[i + j];
        float g0 = __bfloat162float(x[(size_t)(e0.x & 0xFFFFF) * HID + lane]);
        atomicAdd(&yt[((e0.x >> 20) << 6) + lane], __int_as_float(e0.y) * g0);
      }
    }
  }
  __syncthreads();

  // epilogue: partial = sum_rows relu(y2) . Wout → one atomic per block
  const int node0 = b * ROWS_PER_BKT;
  const float wf = Wout[lane];
  float acc = 0.f;
  for (int nn = g; nn < ROWS_PER_BKT; nn += 4) {
    if (node0 + nn >= n) break;
    acc += fmaxf(yt[nn * HID + lane], 0.f) * wf;
  }
  for (int off = 32; off; off >>= 1) acc += __shfl_down(acc, off, 64);
  __shared__ float part[4];
  if (lane == 0) part[g] = acc;
  __syncthreads();
  if (t == 0) {
    float s = part[0] + part[1] + part[2] + part[3];
    if (b == 0) s += bout[0];
    atomicAdd(out, s);
  }
}

extern "C" void kernel_launch(void* const* d_in, const int* in_sizes, int n_in,
                              void* d_out, int out_size, void* d_ws, size_t ws_size,
                              hipStream_t stream) {
  const float* emb  = (const float*)d_in[0];
  const float* deg  = (const float*)d_in[1];
  const float* seed = (const float*)d_in[2];
  const int*   row  = (const int*)d_in[3];
  const int*   col  = (const int*)d_in[4];
  const float* vals = (const float*)d_in[5];
  const float* W1   = (const float*)d_in[6];
  const float* b1   = (const float*)d_in[7];
  const float* W2   = (const float*)d_in[8];
  const float* b2   = (const float*)d_in[9];
  const float* Wout = (const float*)d_in[10];
  const float* bout = (const float*)d_in[11];
  float* out = (float*)d_out;

  const int n  = in_sizes[0] / IN_EMB;   // 100000
  const int nE = in_sizes[3];            // 3200000
  const int nbkt = (n + ROWS_PER_BKT - 1) / ROWS_PER_BKT;   // 782

  // ---- workspace layout ----
  char* ws = (char*)d_ws;
  bf16* xa = (bf16*)ws;                  ws += ((size_t)n * HID * 2 + 255) & ~255ULL;
  bf16* xb = (bf16*)ws;                  ws += ((size_t)n * HID * 2 + 255) & ~255ULL;
  int2* tmp = (int2*)ws;                 ws += (size_t)nE * sizeof(int2);
  int* bcnt   = (int*)ws;                ws += ((size_t)nbkt * 4 + 255) & ~255ULL;
  int* bstart = (int*)ws;                ws += ((size_t)(nbkt + 1) * 4 + 255) & ~255ULL;
  int* bcur   = (int*)ws;

  const int node_blocks = (n + 31) / 32;
  const int part_blocks = (nE + PART_CHUNK - 1) / PART_CHUNK;

  // ---- bucket partition (amortized over both SpMMs) ----
  hipMemsetAsync(bcnt, 0, (size_t)nbkt * sizeof(int), stream);
  bhist_kernel<<<512, 256, 0, stream>>>(row, bcnt, nE, nbkt);
  bscan_kernel<<<1, 1024, 0, stream>>>(bcnt, bstart, bcur, nbkt);
  partition_kernel<<<part_blocks, 256, 0, stream>>>(row, col, vals, bcur, tmp, nE);

  // ---- network ----
  lin1_kernel<<<node_blocks, 256, 0, stream>>>(emb, deg, seed, W1, b1, xa, n);
  spmm1_kernel<<<nbkt, 256, 0, stream>>>(bstart, tmp, xa, W2, b2, xb, n);
  hipMemsetAsync(out, 0, sizeof(float), stream);
  spmm2_kernel<<<nbkt, 256, 0, stream>>>(bstart, tmp, xb, Wout, bout, out, n);
}

// Round 4
// 696.808 us; speedup vs baseline: 4.5186x; 4.5186x over previous
//
#include <hip/hip_runtime.h>
#include <hip/hip_bf16.h>

#define HID 64
#define IN_EMB 128
#define IN_DIM 130
#define ROWS_PER_BKT 128
#define LOG_RPB 7
#define MAX_BKT 1024          // 100000/128 = 782 buckets actually used
#define PART_CHUNK 16384      // edges per partition block

typedef __hip_bfloat16 bf16;

// ---------------- coarse histogram over row-buckets --------------------------
__global__ __launch_bounds__(256) void bhist_kernel(const int* __restrict__ row,
                                                    int* __restrict__ bcnt,
                                                    int nE, int nbkt) {
  __shared__ int h[MAX_BKT];
  for (int i = threadIdx.x; i < nbkt; i += 256) h[i] = 0;
  __syncthreads();
  const int stride = gridDim.x * 256;
  for (int e = blockIdx.x * 256 + threadIdx.x; e < nE; e += stride)
    atomicAdd(&h[row[e] >> LOG_RPB], 1);
  __syncthreads();
  for (int i = threadIdx.x; i < nbkt; i += 256)
    if (h[i]) atomicAdd(&bcnt[i], h[i]);
}

// ---------------- exclusive scan of bucket counts (1 block) ------------------
__global__ __launch_bounds__(1024) void bscan_kernel(const int* __restrict__ bcnt,
                                                     int* __restrict__ bstart,
                                                     int* __restrict__ bcur,
                                                     int* __restrict__ row_ptr,
                                                     int n, int nbkt) {
  __shared__ int s[1024];
  const int t = threadIdx.x;
  const int v = (t < nbkt) ? bcnt[t] : 0;
  s[t] = v;
  __syncthreads();
  for (int off = 1; off < 1024; off <<= 1) {
    int u = (t >= off) ? s[t - off] : 0;
    __syncthreads();
    s[t] += u;
    __syncthreads();
  }
  if (t < nbkt) { int ex = s[t] - v; bstart[t] = ex; bcur[t] = ex; }
  if (t == 0) { bstart[nbkt] = s[1023]; row_ptr[n] = s[1023]; }   // == nE
}

// ---------------- partition edges into row-buckets (coalesced runs) ----------
// packed edge: .x = col | (local_row << 20), .y = bits(val)
__global__ __launch_bounds__(256) void partition_kernel(
    const int* __restrict__ row, const int* __restrict__ col,
    const float* __restrict__ vals, int* __restrict__ bcur,
    int2* __restrict__ tmp, int nE) {
  __shared__ int h[MAX_BKT];
  __shared__ int cur[MAX_BKT];
  const int t = threadIdx.x;
  const int base = blockIdx.x * PART_CHUNK;
  for (int i = t; i < MAX_BKT; i += 256) h[i] = 0;
  __syncthreads();
  for (int k = 0; k < PART_CHUNK / 256; ++k) {
    int e = base + k * 256 + t;
    if (e < nE) atomicAdd(&h[row[e] >> LOG_RPB], 1);
  }
  __syncthreads();
  for (int b = t; b < MAX_BKT; b += 256)
    if (h[b] > 0) cur[b] = atomicAdd(&bcur[b], h[b]);
  __syncthreads();
  for (int k = 0; k < PART_CHUNK / 256; ++k) {
    int e = base + k * 256 + t;
    if (e < nE) {
      int r = row[e];
      int b = r >> LOG_RPB;
      int p = atomicAdd(&cur[b], 1);
      tmp[p] = make_int2(col[e] | ((r & (ROWS_PER_BKT - 1)) << 20),
                         __float_as_int(vals[e]));
    }
  }
}

// ---------------- per-bucket counting sort -> exact CSR + row_ptr ------------
__global__ __launch_bounds__(256) void bucket_sort_kernel(
    const int* __restrict__ bstart, const int2* __restrict__ tmp,
    int2* __restrict__ ce, int* __restrict__ row_ptr, int n) {
  __shared__ int rcnt[ROWS_PER_BKT];
  __shared__ int rpos[ROWS_PER_BKT];
  __shared__ int sc[ROWS_PER_BKT];
  const int t = threadIdx.x;
  const int b = blockIdx.x;
  const int start = bstart[b];
  const int end   = bstart[b + 1];
  if (t < ROWS_PER_BKT) rcnt[t] = 0;
  __syncthreads();
  // pass 1: count local rows
  for (int i = start + t; i < end; i += 256)
    atomicAdd(&rcnt[tmp[i].x >> 20], 1);
  __syncthreads();
  // exclusive scan of 128 counts (Hillis-Steele; all threads hit barriers)
  if (t < ROWS_PER_BKT) sc[t] = rcnt[t];
  __syncthreads();
  for (int off = 1; off < ROWS_PER_BKT; off <<= 1) {
    int u = (t < ROWS_PER_BKT && t >= off) ? sc[t - off] : 0;
    __syncthreads();
    if (t < ROWS_PER_BKT) sc[t] += u;
    __syncthreads();
  }
  if (t < ROWS_PER_BKT) {
    int ex = sc[t] - rcnt[t];
    int gpos = start + ex;
    rpos[t] = gpos;
    int gr = b * ROWS_PER_BKT + t;
    if (gr < n) row_ptr[gr] = gpos;
  }
  __syncthreads();
  // pass 2: scatter into exact row order (within 32KB window -> L2 absorbs)
  for (int i = start + t; i < end; i += 256) {
    int2 e = tmp[i];
    int p = atomicAdd(&rpos[e.x >> 20], 1);
    ce[p] = make_int2(e.x & 0xFFFFF, e.y);
  }
}

// ---------------- Linear1: bf16 activations out ------------------------------
__global__ __launch_bounds__(256) void lin1_kernel(
    const float* __restrict__ emb, const float* __restrict__ deg,
    const float* __restrict__ seed, const float* __restrict__ W1,
    const float* __restrict__ b1, bf16* __restrict__ out, int n) {
  __shared__ float sW[IN_DIM * HID];
  for (int i = threadIdx.x; i < IN_DIM * HID; i += 256) sW[i] = W1[i];
  __syncthreads();
  const int lane = threadIdx.x & 63;
  const int g    = threadIdx.x >> 6;
  const int base = blockIdx.x * 32;
  for (int nn = g; nn < 32; nn += 4) {
    const int node = base + nn;
    if (node >= n) continue;
    float acc = b1[lane];
    const float* e = emb + (size_t)node * IN_EMB;
#pragma unroll 8
    for (int k = 0; k < IN_EMB; ++k) acc += e[k] * sW[k * HID + lane];
    acc += deg[node]  * sW[IN_EMB * HID + lane];
    acc += seed[node] * sW[(IN_EMB + 1) * HID + lane];
    out[(size_t)node * HID + lane] = __float2bfloat16(acc);
  }
}

// ---------------- SpMM (exact CSR, gather-only, bf16) + fused ReLU -----------
__global__ __launch_bounds__(256) void spmm_csr_kernel(
    const int* __restrict__ row_ptr, const int2* __restrict__ ce,
    const bf16* __restrict__ x, bf16* __restrict__ y, int n) {
  const int lane = threadIdx.x & 63;
  const int r = blockIdx.x * 4 + (threadIdx.x >> 6);
  if (r >= n) return;
  int i = row_ptr[r];
  const int end = row_ptr[r + 1];
  float acc = 0.f;
  for (; i + 8 <= end; i += 8) {
    int2 e0 = ce[i],   e1 = ce[i+1], e2 = ce[i+2], e3 = ce[i+3];
    int2 e4 = ce[i+4], e5 = ce[i+5], e6 = ce[i+6], e7 = ce[i+7];
    float g0 = __bfloat162float(x[(size_t)e0.x * HID + lane]);
    float g1 = __bfloat162float(x[(size_t)e1.x * HID + lane]);
    float g2 = __bfloat162float(x[(size_t)e2.x * HID + lane]);
    float g3 = __bfloat162float(x[(size_t)e3.x * HID + lane]);
    float g4 = __bfloat162float(x[(size_t)e4.x * HID + lane]);
    float g5 = __bfloat162float(x[(size_t)e5.x * HID + lane]);
    float g6 = __bfloat162float(x[(size_t)e6.x * HID + lane]);
    float g7 = __bfloat162float(x[(size_t)e7.x * HID + lane]);
    acc += __int_as_float(e0.y) * g0 + __int_as_float(e1.y) * g1
         + __int_as_float(e2.y) * g2 + __int_as_float(e3.y) * g3
         + __int_as_float(e4.y) * g4 + __int_as_float(e5.y) * g5
         + __int_as_float(e6.y) * g6 + __int_as_float(e7.y) * g7;
  }
  for (; i < end; ++i) {
    int2 e0 = ce[i];
    acc += __int_as_float(e0.y) * __bfloat162float(x[(size_t)e0.x * HID + lane]);
  }
  y[(size_t)r * HID + lane] = __float2bfloat16(fmaxf(acc, 0.f));   // fused ReLU
}

// ---------------- Linear2 (input already ReLU'd, bf16) -----------------------
__global__ __launch_bounds__(256) void lin2_kernel(
    const bf16* __restrict__ yin, const float* __restrict__ W2,
    const float* __restrict__ b2, bf16* __restrict__ xout, int n) {
  __shared__ float sW[HID * HID];
  for (int i = threadIdx.x; i < HID * HID; i += 256) sW[i] = W2[i];
  __syncthreads();
  const int lane = threadIdx.x & 63;
  const int g    = threadIdx.x >> 6;
  const int base = blockIdx.x * 32;
  for (int nn = g; nn < 32; nn += 4) {
    const int node = base + nn;
    if (node >= n) continue;
    float acc = b2[lane];
    const bf16* yrow = yin + (size_t)node * HID;
#pragma unroll 8
    for (int k = 0; k < HID; ++k)
      acc += __bfloat162float(yrow[k]) * sW[k * HID + lane];
    xout[(size_t)node * HID + lane] = __float2bfloat16(acc);
  }
}

// ---------------- Final reduce (input already ReLU'd, bf16) ------------------
__global__ __launch_bounds__(256) void final_kernel(
    const bf16* __restrict__ y, const float* __restrict__ Wout,
    const float* __restrict__ bout, float* __restrict__ out, int n) {
  const int lane = threadIdx.x & 63;
  const int g    = threadIdx.x >> 6;
  const float wf = Wout[lane];
  float acc = 0.f;
  const int start  = blockIdx.x * 4 + g;
  const int stride = gridDim.x * 4;
  for (int i = start; i < n; i += stride)
    acc += __bfloat162float(y[(size_t)i * HID + lane]) * wf;
  for (int off = 32; off; off >>= 1) acc += __shfl_down(acc, off, 64);
  __shared__ float part[4];
  if (lane == 0) part[g] = acc;
  __syncthreads();
  if (threadIdx.x == 0) {
    float s = part[0] + part[1] + part[2] + part[3];
    if (blockIdx.x == 0) s += bout[0];
    atomicAdd(out, s);
  }
}

extern "C" void kernel_launch(void* const* d_in, const int* in_sizes, int n_in,
                              void* d_out, int out_size, void* d_ws, size_t ws_size,
                              hipStream_t stream) {
  const float* emb  = (const float*)d_in[0];
  const float* deg  = (const float*)d_in[1];
  const float* seed = (const float*)d_in[2];
  const int*   row  = (const int*)d_in[3];
  const int*   col  = (const int*)d_in[4];
  const float* vals = (const float*)d_in[5];
  const float* W1   = (const float*)d_in[6];
  const float* b1   = (const float*)d_in[7];
  const float* W2   = (const float*)d_in[8];
  const float* b2   = (const float*)d_in[9];
  const float* Wout = (const float*)d_in[10];
  const float* bout = (const float*)d_in[11];
  float* out = (float*)d_out;

  const int n  = in_sizes[0] / IN_EMB;   // 100000
  const int nE = in_sizes[3];            // 3200000
  const int nbkt = (n + ROWS_PER_BKT - 1) / ROWS_PER_BKT;   // 782

  // ---- workspace layout (with aliasing; ~77 MB total like round 2) ----
  char* ws = (char*)d_ws;
  int2* ce   = (int2*)ws;  ws += (size_t)nE * sizeof(int2);            // 25.6 MB, live to end
  char* tmpb = ws;
  int2* tmp  = (int2*)ws;  ws += (size_t)nE * sizeof(int2);            // 25.6 MB, dead after sort
  bf16* xa   = (bf16*)ws;  ws += ((size_t)n * HID * 2 + 255) & ~255ULL; // 12.8 MB
  bf16* xb   = (bf16*)ws;  ws += ((size_t)n * HID * 2 + 255) & ~255ULL; // 12.8 MB
  int* row_ptr = (int*)ws; ws += ((size_t)(n + 1) * 4 + 255) & ~255ULL;
  int* bcnt    = (int*)ws; ws += ((size_t)nbkt * 4 + 255) & ~255ULL;
  int* bstart  = (int*)ws; ws += ((size_t)(nbkt + 1) * 4 + 255) & ~255ULL;
  int* bcur    = (int*)ws;
  bf16* ya = (bf16*)tmpb;   // alias: tmp dead before spmm1 writes ya
  bf16* yb = xa;            // alias: xa dead before spmm2 writes yb

  const int node_blocks = (n + 31) / 32;
  const int row_blocks  = (n + 3) / 4;
  const int part_blocks = (nE + PART_CHUNK - 1) / PART_CHUNK;

  // ---- CSR build: coarse partition + per-bucket counting sort ----
  hipMemsetAsync(bcnt, 0, (size_t)nbkt * sizeof(int), stream);
  bhist_kernel<<<512, 256, 0, stream>>>(row, bcnt, nE, nbkt);
  bscan_kernel<<<1, 1024, 0, stream>>>(bcnt, bstart, bcur, row_ptr, n, nbkt);
  partition_kernel<<<part_blocks, 256, 0, stream>>>(row, col, vals, bcur, tmp, nE);
  bucket_sort_kernel<<<nbkt, 256, 0, stream>>>(bstart, tmp, ce, row_ptr, n);

  // ---- network ----
  lin1_kernel<<<node_blocks, 256, 0, stream>>>(emb, deg, seed, W1, b1, xa, n);
  spmm_csr_kernel<<<row_blocks, 256, 0, stream>>>(row_ptr, ce, xa, ya, n);   // relu fused
  lin2_kernel<<<node_blocks, 256, 0, stream>>>(ya, W2, b2, xb, n);
  spmm_csr_kernel<<<row_blocks, 256, 0, stream>>>(row_ptr, ce, xb, yb, n);   // relu fused
  hipMemsetAsync(out, 0, sizeof(float), stream);
  final_kernel<<<1024, 256, 0, stream>>>(yb, Wout, bout, out, n);
}